// Round 2
// baseline (56.838 us; speedup 1.0000x reference)
//
#include <hip/hip_runtime.h>
#include <hip/hip_bf16.h>

#define N_PARENT 4
#define N_CHILD 8
#define SINKHORN_ITERS 20
#define INV_TEMP 10.0f  // 1/0.1

// ---------------------------------------------------------------------------
// Kernel 1: compute temporal_masks (8 x 4) from log_alpha, sign_logits,
// logic_masks. One block, lanes 0..31 each own one (i,j) of the 4x8 matrix.
// lane layout: idx = i*8 + j  (i = parent 0..3, j = child 0..7)
//   column LSE (over i)  -> shfl_xor 8, 16
//   row    LSE (over j)  -> shfl_xor 1, 2, 4
// ---------------------------------------------------------------------------
__global__ void sinkhorn_table_kernel(const float* __restrict__ logic_masks, // (4,4)
                                      const float* __restrict__ log_alpha,   // (4,8)
                                      const float* __restrict__ sign_logits, // (8,)
                                      float* __restrict__ tm /* (8,4) out */) {
    const int lane = threadIdx.x & 63;
    const int idx  = lane & 31;           // lanes 32..63 mirror 0..31
    const int i    = idx >> 3;            // parent
    const int j    = idx & 7;             // child

    float la = log_alpha[i * N_CHILD + j] * INV_TEMP;
    const float log_row_target = 0.6931471805599453f; // log(8/4)

    #pragma unroll 1
    for (int it = 0; it < SINKHORN_ITERS; ++it) {
        // ---- column logsumexp (reduce over i: xor 8, 16) ----
        float m = la;
        m = fmaxf(m, __shfl_xor(m, 8));
        m = fmaxf(m, __shfl_xor(m, 16));
        float e = expf(la - m);
        e += __shfl_xor(e, 8);
        e += __shfl_xor(e, 16);
        la = la - (m + logf(e));
        // ---- row logsumexp (reduce over j: xor 1, 2, 4) ----
        m = la;
        m = fmaxf(m, __shfl_xor(m, 1));
        m = fmaxf(m, __shfl_xor(m, 2));
        m = fmaxf(m, __shfl_xor(m, 4));
        e = expf(la - m);
        e += __shfl_xor(e, 1);
        e += __shfl_xor(e, 2);
        e += __shfl_xor(e, 4);
        la = la + log_row_target - (m + logf(e));
    }

    const float P = expf(la);
    const float s = tanhf(sign_logits[j] * INV_TEMP);
    const float R = P * s;

    // temporal_masks[j][mm] = sum_i R(i,j) * logic_masks[i][mm]
    #pragma unroll
    for (int mm = 0; mm < 4; ++mm) {
        float t = R * logic_masks[i * 4 + mm];
        t += __shfl_xor(t, 8);
        t += __shfl_xor(t, 16);
        if (lane < 8) tm[j * 4 + mm] = t;   // lane<8 => i==0, lower half only
    }
}

// ---------------------------------------------------------------------------
// Kernel 2: streaming map. float4/int4 vectorized, grid-stride.
// out[k] = tanh(10 * (m0 + a*m1 + b*m2 + a*b*m3)), m = temporal_masks[op[k]]
// ---------------------------------------------------------------------------
__global__ __launch_bounds__(256) void
phase2a_apply_kernel(const float* __restrict__ a,
                     const float* __restrict__ b,
                     const int*   __restrict__ op,
                     const float* __restrict__ tm,  // (8,4) in d_ws
                     float*       __restrict__ out,
                     int n4) {
    __shared__ float4 s_tm[N_CHILD];
    if (threadIdx.x < N_CHILD) {
        const float4* tm4 = reinterpret_cast<const float4*>(tm);
        s_tm[threadIdx.x] = tm4[threadIdx.x];
    }
    __syncthreads();

    const float4* __restrict__ a4  = reinterpret_cast<const float4*>(a);
    const float4* __restrict__ b4  = reinterpret_cast<const float4*>(b);
    const int4*   __restrict__ op4 = reinterpret_cast<const int4*>(op);
    float4*       __restrict__ o4  = reinterpret_cast<float4*>(out);

    const int stride = gridDim.x * blockDim.x;
    for (int t = blockIdx.x * blockDim.x + threadIdx.x; t < n4; t += stride) {
        float4 av = a4[t];
        float4 bv = b4[t];
        int4   ov = op4[t];

        float4 r;
        {
            float4 m = s_tm[ov.x & 7];
            r.x = tanhf(10.0f * (m.x + av.x * m.y + bv.x * m.z + av.x * bv.x * m.w));
        }
        {
            float4 m = s_tm[ov.y & 7];
            r.y = tanhf(10.0f * (m.x + av.y * m.y + bv.y * m.z + av.y * bv.y * m.w));
        }
        {
            float4 m = s_tm[ov.z & 7];
            r.z = tanhf(10.0f * (m.x + av.z * m.y + bv.z * m.z + av.z * bv.z * m.w));
        }
        {
            float4 m = s_tm[ov.w & 7];
            r.w = tanhf(10.0f * (m.x + av.w * m.y + bv.w * m.z + av.w * bv.w * m.w));
        }
        o4[t] = r;
    }
}

extern "C" void kernel_launch(void* const* d_in, const int* in_sizes, int n_in,
                              void* d_out, int out_size, void* d_ws, size_t ws_size,
                              hipStream_t stream) {
    const float* a           = (const float*)d_in[0];
    const float* b           = (const float*)d_in[1];
    const int*   op          = (const int*)d_in[2];
    const float* logic_masks = (const float*)d_in[3];
    const float* log_alpha   = (const float*)d_in[4];
    const float* sign_logits = (const float*)d_in[5];
    float*       out         = (float*)d_out;
    float*       tm          = (float*)d_ws;   // 32 floats

    const int n  = in_sizes[0];
    const int n4 = n >> 2;                     // B = 2^24, divisible by 4

    sinkhorn_table_kernel<<<1, 64, 0, stream>>>(logic_masks, log_alpha, sign_logits, tm);

    int blocks = (n4 + 255) / 256;
    if (blocks > 2048) blocks = 2048;
    phase2a_apply_kernel<<<blocks, 256, 0, stream>>>(a, b, op, tm, out, n4);
}

// Round 3
// 54.779 us; speedup vs baseline: 1.0376x; 1.0376x over previous
//
#include <hip/hip_runtime.h>
#include <hip/hip_bf16.h>

#define N_PARENT 4
#define N_CHILD 8
#define SINKHORN_ITERS 20
#define INV_TEMP 10.0f  // 1/0.1

typedef float f4 __attribute__((ext_vector_type(4)));
typedef int   i4 __attribute__((ext_vector_type(4)));

// ---------------------------------------------------------------------------
// Kernel 1: compute temporal_masks (8 x 4) from log_alpha, sign_logits,
// logic_masks. One block, lanes 0..31 each own one (i,j) of the 4x8 matrix.
// lane layout: idx = i*8 + j  (i = parent 0..3, j = child 0..7)
//   column LSE (over i)  -> shfl_xor 8, 16
//   row    LSE (over j)  -> shfl_xor 1, 2, 4
// The table is stored PRE-SCALED by 20*log2(e) so the streaming kernel can
// compute tanh(10*dot) = 1 - 2/(2^(dot') + 1) with a single v_exp_f32.
// ---------------------------------------------------------------------------
__global__ void sinkhorn_table_kernel(const float* __restrict__ logic_masks, // (4,4)
                                      const float* __restrict__ log_alpha,   // (4,8)
                                      const float* __restrict__ sign_logits, // (8,)
                                      float* __restrict__ tm /* (8,4) out */) {
    const int lane = threadIdx.x & 63;
    const int idx  = lane & 31;           // lanes 32..63 mirror 0..31
    const int i    = idx >> 3;            // parent
    const int j    = idx & 7;             // child

    float la = log_alpha[i * N_CHILD + j] * INV_TEMP;
    const float log_row_target = 0.6931471805599453f; // log(8/4)

    #pragma unroll 1
    for (int it = 0; it < SINKHORN_ITERS; ++it) {
        // ---- column logsumexp (reduce over i: xor 8, 16) ----
        float m = la;
        m = fmaxf(m, __shfl_xor(m, 8));
        m = fmaxf(m, __shfl_xor(m, 16));
        float e = expf(la - m);
        e += __shfl_xor(e, 8);
        e += __shfl_xor(e, 16);
        la = la - (m + logf(e));
        // ---- row logsumexp (reduce over j: xor 1, 2, 4) ----
        m = la;
        m = fmaxf(m, __shfl_xor(m, 1));
        m = fmaxf(m, __shfl_xor(m, 2));
        m = fmaxf(m, __shfl_xor(m, 4));
        e = expf(la - m);
        e += __shfl_xor(e, 1);
        e += __shfl_xor(e, 2);
        e += __shfl_xor(e, 4);
        la = la + log_row_target - (m + logf(e));
    }

    const float P = expf(la);
    const float s = tanhf(sign_logits[j] * INV_TEMP);
    const float R = P * s;

    // scale = 2 * 10 / ln(2): tanh(10*d) = 1 - 2/(exp(20 d)+1) = 1 - 2/(2^(d*scale)+1)
    const float scale = 28.853900817779268f; // 20 * log2(e)

    // temporal_masks[j][mm] = sum_i R(i,j) * logic_masks[i][mm], prescaled
    #pragma unroll
    for (int mm = 0; mm < 4; ++mm) {
        float t = R * logic_masks[i * 4 + mm];
        t += __shfl_xor(t, 8);
        t += __shfl_xor(t, 16);
        if (lane < 8) tm[j * 4 + mm] = t * scale;   // lane<8 => i==0
    }
}

// ---------------------------------------------------------------------------
// Kernel 2: streaming map, one-shot (no grid-stride loop), 2 float4 groups
// per thread (front half + back half) for 6 independent loads in flight.
// out = tanh(10*dot) computed branch-free: 1 - 2*rcp(2^(dot') + 1).
// ---------------------------------------------------------------------------
__device__ __forceinline__ float4 apply4(f4 av, f4 bv, i4 ov, const f4* s_tm) {
    float4 r;
    {
        f4 m = s_tm[ov.x & 7];
        float d = m.x + av.x * m.y + bv.x * m.z + av.x * bv.x * m.w;
        r.x = 1.0f - 2.0f * __builtin_amdgcn_rcpf(__builtin_amdgcn_exp2f(d) + 1.0f);
    }
    {
        f4 m = s_tm[ov.y & 7];
        float d = m.x + av.y * m.y + bv.y * m.z + av.y * bv.y * m.w;
        r.y = 1.0f - 2.0f * __builtin_amdgcn_rcpf(__builtin_amdgcn_exp2f(d) + 1.0f);
    }
    {
        f4 m = s_tm[ov.z & 7];
        float d = m.x + av.z * m.y + bv.z * m.z + av.z * bv.z * m.w;
        r.z = 1.0f - 2.0f * __builtin_amdgcn_rcpf(__builtin_amdgcn_exp2f(d) + 1.0f);
    }
    {
        f4 m = s_tm[ov.w & 7];
        float d = m.x + av.w * m.y + bv.w * m.z + av.w * bv.w * m.w;
        r.w = 1.0f - 2.0f * __builtin_amdgcn_rcpf(__builtin_amdgcn_exp2f(d) + 1.0f);
    }
    return r;
}

__global__ __launch_bounds__(256) void
phase2a_apply_kernel(const float* __restrict__ a,
                     const float* __restrict__ b,
                     const int*   __restrict__ op,
                     const float* __restrict__ tm,  // (8,4) prescaled, in d_ws
                     float*       __restrict__ out,
                     int half /* n4/2 */) {
    __shared__ f4 s_tm[N_CHILD];
    if (threadIdx.x < N_CHILD) {
        s_tm[threadIdx.x] = reinterpret_cast<const f4*>(tm)[threadIdx.x];
    }
    __syncthreads();

    const f4* __restrict__ a4  = reinterpret_cast<const f4*>(a);
    const f4* __restrict__ b4  = reinterpret_cast<const f4*>(b);
    const i4* __restrict__ op4 = reinterpret_cast<const i4*>(op);
    f4*       __restrict__ o4  = reinterpret_cast<f4*>(out);

    const int t = blockIdx.x * 256 + threadIdx.x;
    if (t >= half) return;
    const int t2 = t + half;

    // issue all 6 loads before any use
    f4 av0 = a4[t];
    f4 bv0 = b4[t];
    i4 ov0 = op4[t];
    f4 av1 = a4[t2];
    f4 bv1 = b4[t2];
    i4 ov1 = op4[t2];

    float4 r0 = apply4(av0, bv0, ov0, s_tm);
    float4 r1 = apply4(av1, bv1, ov1, s_tm);

    f4 w0 = { r0.x, r0.y, r0.z, r0.w };
    f4 w1 = { r1.x, r1.y, r1.z, r1.w };
    __builtin_nontemporal_store(w0, &o4[t]);
    __builtin_nontemporal_store(w1, &o4[t2]);
}

extern "C" void kernel_launch(void* const* d_in, const int* in_sizes, int n_in,
                              void* d_out, int out_size, void* d_ws, size_t ws_size,
                              hipStream_t stream) {
    const float* a           = (const float*)d_in[0];
    const float* b           = (const float*)d_in[1];
    const int*   op          = (const int*)d_in[2];
    const float* logic_masks = (const float*)d_in[3];
    const float* log_alpha   = (const float*)d_in[4];
    const float* sign_logits = (const float*)d_in[5];
    float*       out         = (float*)d_out;
    float*       tm          = (float*)d_ws;   // 32 floats

    const int n    = in_sizes[0];
    const int n4   = n >> 2;                   // B = 2^24 divisible by 4
    const int half = n4 >> 1;                  // and by 8

    sinkhorn_table_kernel<<<1, 64, 0, stream>>>(logic_masks, log_alpha, sign_logits, tm);

    const int blocks = (half + 255) / 256;     // exact one-shot grid
    phase2a_apply_kernel<<<blocks, 256, 0, stream>>>(a, b, op, tm, out, half);
}

// Round 5
// 46.094 us; speedup vs baseline: 1.2331x; 1.1884x over previous
//
#include <hip/hip_runtime.h>

#define SINKHORN_ITERS 20

typedef float f4 __attribute__((ext_vector_type(4)));
typedef int   i4 __attribute__((ext_vector_type(4)));

// tanh(10*d) = 1 - 2/(2^(d * 20*log2e) + 1); table is prescaled by 20*log2e.
__device__ __forceinline__ float fast_out(float d_prescaled) {
    return 1.0f - 2.0f * __builtin_amdgcn_rcpf(__builtin_amdgcn_exp2f(d_prescaled) + 1.0f);
}

__device__ __forceinline__ f4 apply4(f4 av, f4 bv, i4 ov, const f4* s_tm) {
    f4 r;
    {
        f4 m = s_tm[ov.x & 7];
        r.x = fast_out(m.x + av.x * m.y + bv.x * m.z + av.x * bv.x * m.w);
    }
    {
        f4 m = s_tm[ov.y & 7];
        r.y = fast_out(m.x + av.y * m.y + bv.y * m.z + av.y * bv.y * m.w);
    }
    {
        f4 m = s_tm[ov.z & 7];
        r.z = fast_out(m.x + av.z * m.y + bv.z * m.z + av.z * bv.z * m.w);
    }
    {
        f4 m = s_tm[ov.w & 7];
        r.w = fast_out(m.x + av.w * m.y + bv.w * m.z + av.w * bv.w * m.w);
    }
    return r;
}

// ---------------------------------------------------------------------------
// Single fused kernel. Per block:
//   1. all threads issue their 6 global loads (2 float4 segments at half
//      stride -> latency hides under the table computation)
//   2. wave 0 computes the 4x8 Sinkhorn in-register (lanes = (i,j) of the
//      matrix; col LSE = shfl_xor 8,16; row LSE = shfl_xor 1,2,4; max-free:
//      arguments are bounded, exp2 args <= ~80) and writes the prescaled
//      8 x float4 temporal_masks table to LDS
//   3. __syncthreads, consume, nontemporal store (keep L3 for inputs)
// No d_ws, no second kernel, no cross-dispatch producer/consumer edge.
// ---------------------------------------------------------------------------
__global__ __launch_bounds__(256) void
phase2a_fused_kernel(const float* __restrict__ a,
                     const float* __restrict__ b,
                     const int*   __restrict__ op,
                     const float* __restrict__ logic_masks, // (4,4)
                     const float* __restrict__ log_alpha,   // (4,8)
                     const float* __restrict__ sign_logits, // (8,)
                     float*       __restrict__ out,
                     int half /* n4/2 */) {
    __shared__ f4 s_tm[8];

    const f4* __restrict__ a4  = reinterpret_cast<const f4*>(a);
    const f4* __restrict__ b4  = reinterpret_cast<const f4*>(b);
    const i4* __restrict__ op4 = reinterpret_cast<const i4*>(op);
    f4*       __restrict__ o4  = reinterpret_cast<f4*>(out);

    const int t0 = blockIdx.x * 256 + threadIdx.x;   // exact grid: t0 < half always
    const int t1 = t0 + half;

    // 1. issue all 6 loads before anything else
    f4 av0 = a4[t0];  f4 bv0 = b4[t0];  i4 ov0 = op4[t0];
    f4 av1 = a4[t1];  f4 bv1 = b4[t1];  i4 ov1 = op4[t1];

    // 2. wave 0: Sinkhorn + table build (redundant per block, hidden under loads)
    if (threadIdx.x < 64) {
        const int idx = threadIdx.x & 31;     // lanes 32..63 mirror 0..31
        const int i   = idx >> 3;             // parent 0..3
        const int j   = idx & 7;              // child 0..7

        const float L2E = 1.4426950408889634f;
        const float LN2 = 0.6931471805599453f; // also = log(n_child/n_parent) = log 2

        float la = log_alpha[i * 8 + j] * 10.0f;   // /TEMPERATURE

        #pragma unroll 1
        for (int it = 0; it < SINKHORN_ITERS; ++it) {
            // column logsumexp over i (xor 8, 16), max-free (bounded args)
            float e = __builtin_amdgcn_exp2f(la * L2E);
            e += __shfl_xor(e, 8);
            e += __shfl_xor(e, 16);
            la -= __builtin_amdgcn_logf(e) * LN2;   // v_log_f32 = log2
            // row logsumexp over j (xor 1, 2, 4)
            e = __builtin_amdgcn_exp2f(la * L2E);
            e += __shfl_xor(e, 1);
            e += __shfl_xor(e, 2);
            e += __shfl_xor(e, 4);
            la += LN2 - __builtin_amdgcn_logf(e) * LN2;
        }

        const float scale = 28.853900817779268f;    // 20 * log2(e)
        const float P = __builtin_amdgcn_exp2f(la * L2E);
        const float s = fast_out(sign_logits[j] * scale); // tanh(sl/T), same identity
        const float R = P * s;

        f4 row;
        #pragma unroll
        for (int mm = 0; mm < 4; ++mm) {
            float t = R * logic_masks[i * 4 + mm];
            t += __shfl_xor(t, 8);
            t += __shfl_xor(t, 16);
            row[mm] = t * scale;
        }
        if (threadIdx.x < 8) s_tm[threadIdx.x] = row;  // lanes 0..7 have i==0, j==lane
    }
    __syncthreads();

    // 3. consume + nontemporal store
    f4 r0 = apply4(av0, bv0, ov0, s_tm);
    f4 r1 = apply4(av1, bv1, ov1, s_tm);
    __builtin_nontemporal_store(r0, &o4[t0]);
    __builtin_nontemporal_store(r1, &o4[t1]);
}

extern "C" void kernel_launch(void* const* d_in, const int* in_sizes, int n_in,
                              void* d_out, int out_size, void* d_ws, size_t ws_size,
                              hipStream_t stream) {
    const float* a           = (const float*)d_in[0];
    const float* b           = (const float*)d_in[1];
    const int*   op          = (const int*)d_in[2];
    const float* logic_masks = (const float*)d_in[3];
    const float* log_alpha   = (const float*)d_in[4];
    const float* sign_logits = (const float*)d_in[5];
    float*       out         = (float*)d_out;
    (void)d_ws; (void)ws_size;

    const int n    = in_sizes[0];
    const int n4   = n >> 2;     // 2^22 for B = 2^24
    const int half = n4 >> 1;    // 2^21

    const int blocks = half / 256;  // 8192, exact
    phase2a_fused_kernel<<<blocks, 256, 0, stream>>>(a, b, op, logic_masks,
                                                     log_alpha, sign_logits,
                                                     out, half);
}

// Round 6
// 44.751 us; speedup vs baseline: 1.2701x; 1.0300x over previous
//
#include <hip/hip_runtime.h>

#define SINKHORN_ITERS 20

typedef float f4 __attribute__((ext_vector_type(4)));
typedef int   i4 __attribute__((ext_vector_type(4)));

// butterfly add with lane permutation done via DPP (VALU latency, no LDS pipe)
// CTRL: 0xB1 = quad_perm [1,0,3,2] (xor1), 0x4E = quad_perm [2,3,0,1] (xor2),
//       0x141 = row_half_mirror (xor7), 0x128 = row_ror:8 (xor8)
template <int CTRL>
__device__ __forceinline__ float dpp_xadd(float x) {
    int yi = __builtin_amdgcn_update_dpp(0, __builtin_bit_cast(int, x),
                                         CTRL, 0xF, 0xF, true);
    return x + __builtin_bit_cast(float, yi);
}

// tanh(10*d) = 1 - 2/(2^(d * 20*log2e) + 1); table is prescaled by 20*log2e.
__device__ __forceinline__ float fast_out(float d_prescaled) {
    return 1.0f - 2.0f * __builtin_amdgcn_rcpf(__builtin_amdgcn_exp2f(d_prescaled) + 1.0f);
}

__device__ __forceinline__ f4 apply4(f4 av, f4 bv, i4 ov, const f4* s_tm) {
    f4 r;
    {
        f4 m = s_tm[ov.x & 7];
        r.x = fast_out(m.x + av.x * m.y + bv.x * m.z + av.x * bv.x * m.w);
    }
    {
        f4 m = s_tm[ov.y & 7];
        r.y = fast_out(m.x + av.y * m.y + bv.y * m.z + av.y * bv.y * m.w);
    }
    {
        f4 m = s_tm[ov.z & 7];
        r.z = fast_out(m.x + av.z * m.y + bv.z * m.z + av.z * bv.z * m.w);
    }
    {
        f4 m = s_tm[ov.w & 7];
        r.w = fast_out(m.x + av.w * m.y + bv.w * m.z + av.w * bv.w * m.w);
    }
    return r;
}

// ---------------------------------------------------------------------------
// Single fused kernel. Per block:
//   1. all threads issue 6 global loads: 2 ADJACENT float4 segments per array
//      (one contiguous 8 KB run per array per block -> few DRAM streams)
//   2. wave 0 computes the 4x8 Sinkhorn in-register; row/col logsumexp
//      butterflies use DPP adds (xor1/2/7/8) + one ds shuffle (xor16) ->
//      ~0.7 us serial chain, hidden under the loads
//   3. __syncthreads, consume, nontemporal store (keep L3 for inputs)
// ---------------------------------------------------------------------------
__global__ __launch_bounds__(256) void
phase2a_fused_kernel(const float* __restrict__ a,
                     const float* __restrict__ b,
                     const int*   __restrict__ op,
                     const float* __restrict__ logic_masks, // (4,4)
                     const float* __restrict__ log_alpha,   // (4,8)
                     const float* __restrict__ sign_logits, // (8,)
                     float*       __restrict__ out) {
    __shared__ f4 s_tm[8];

    const f4* __restrict__ a4  = reinterpret_cast<const f4*>(a);
    const f4* __restrict__ b4  = reinterpret_cast<const f4*>(b);
    const i4* __restrict__ op4 = reinterpret_cast<const i4*>(op);
    f4*       __restrict__ o4  = reinterpret_cast<f4*>(out);

    const int t0 = blockIdx.x * 512 + threadIdx.x;  // exact grid
    const int t1 = t0 + 256;                        // adjacent segment

    // 1. issue all 6 loads before anything else
    f4 av0 = a4[t0];  f4 bv0 = b4[t0];  i4 ov0 = op4[t0];
    f4 av1 = a4[t1];  f4 bv1 = b4[t1];  i4 ov1 = op4[t1];

    // 2. wave 0: Sinkhorn + table build (redundant per block, hidden under loads)
    if (threadIdx.x < 64) {
        const int idx = threadIdx.x & 31;     // lanes 32..63 mirror 0..31
        const int i   = idx >> 3;             // parent 0..3
        const int j   = idx & 7;              // child 0..7

        const float L2E = 1.4426950408889634f;
        const float LN2 = 0.6931471805599453f; // also = log(n_child/n_parent)

        float la = log_alpha[i * 8 + j] * 10.0f;   // /TEMPERATURE

        #pragma unroll 1
        for (int it = 0; it < SINKHORN_ITERS; ++it) {
            // column logsumexp over i (masks {8,16}), max-free (bounded args)
            float e = __builtin_amdgcn_exp2f(la * L2E);
            e = dpp_xadd<0x128>(e);          // xor8 = row_ror:8
            e += __shfl_xor(e, 16);          // xor16
            la -= __builtin_amdgcn_logf(e) * LN2;
            // row logsumexp over j (masks {1,2,7} — independent, span {0..7})
            e = __builtin_amdgcn_exp2f(la * L2E);
            e = dpp_xadd<0xB1>(e);           // xor1 = quad_perm [1,0,3,2]
            e = dpp_xadd<0x4E>(e);           // xor2 = quad_perm [2,3,0,1]
            e = dpp_xadd<0x141>(e);          // xor7 = row_half_mirror
            la += LN2 - __builtin_amdgcn_logf(e) * LN2;
        }

        const float scale = 28.853900817779268f;    // 20 * log2(e)
        const float P = __builtin_amdgcn_exp2f(la * L2E);
        const float s = fast_out(sign_logits[j] * scale); // tanh(sl/T)
        const float R = P * s;

        f4 row;
        #pragma unroll
        for (int mm = 0; mm < 4; ++mm) {
            float t = R * logic_masks[i * 4 + mm];
            t = dpp_xadd<0x128>(t);          // xor8
            t += __shfl_xor(t, 16);          // xor16
            row[mm] = t * scale;
        }
        if (threadIdx.x < 8) s_tm[threadIdx.x] = row;  // lanes 0..7: i==0, j==lane
    }
    __syncthreads();

    // 3. consume + nontemporal store
    f4 r0 = apply4(av0, bv0, ov0, s_tm);
    f4 r1 = apply4(av1, bv1, ov1, s_tm);
    __builtin_nontemporal_store(r0, &o4[t0]);
    __builtin_nontemporal_store(r1, &o4[t1]);
}

extern "C" void kernel_launch(void* const* d_in, const int* in_sizes, int n_in,
                              void* d_out, int out_size, void* d_ws, size_t ws_size,
                              hipStream_t stream) {
    const float* a           = (const float*)d_in[0];
    const float* b           = (const float*)d_in[1];
    const int*   op          = (const int*)d_in[2];
    const float* logic_masks = (const float*)d_in[3];
    const float* log_alpha   = (const float*)d_in[4];
    const float* sign_logits = (const float*)d_in[5];
    float*       out         = (float*)d_out;
    (void)d_ws; (void)ws_size;

    const int n  = in_sizes[0];
    const int n4 = n >> 2;           // 2^22 for B = 2^24
    const int blocks = n4 / 512;     // 8192, exact (512 float4 per block)

    phase2a_fused_kernel<<<blocks, 256, 0, stream>>>(a, b, op, logic_masks,
                                                     log_alpha, sign_logits, out);
}